// Round 12
// baseline (414.253 us; speedup 1.0000x reference)
//
#include <hip/hip_runtime.h>
#include <hip/hip_bf16.h>
#include <math.h>

#define TM1 16
#define TT 17

typedef __attribute__((ext_vector_type(8))) __bf16 bf16x8;
typedef __attribute__((ext_vector_type(4))) float f32x4;

// ---------------- workspace layout (float units) ----------------
#define OFF_BSTATS 0          // 2048*32 = 65536
#define OFF_STATS  65536      // 32
#define OFF_POOLED 65568      // 2048*16 = 32768
#define OFF_SPB    98336      // 512*256 bf16 = 65536 f
#define OFF_PWB    163872     // 256*512 bf16 = 65536 f
#define OFF_WIHB   229408     // 1536*256 bf16 = 196608 f
#define OFF_WHHB   426016     // 1536*512 bf16 = 393216 f
#define OFF_HB     819232     // 2 x 512*512 bf16 = 262144 f
// total 1081376 floats ~= 4.3 MB

#define IMG_STRIDE 67
#define SLAB_ROWS 18
#define IMG_CI (SLAB_ROWS * IMG_STRIDE)   // 1206

// Slab staging shared by both passes: block = (image b, slab s of 4).
// Slab covers conv rows [s*16, s*16+16); input rows s*16-1 .. s*16+16 (18, zero-padded),
// padded cols 0..65 (input col = c-1).
__device__ __forceinline__ void stage_slab(float* __restrict__ imgp,
                                           const float* __restrict__ xb, int slab, int tid) {
  for (int i = tid; i < 2 * SLAB_ROWS * 66; i += 256) {
    const int ci = i / (SLAB_ROWS * 66);
    const int rem = i - ci * (SLAB_ROWS * 66);
    const int lr = rem / 66, c = rem - lr * 66;
    const int gr = slab * 16 - 1 + lr;
    float v = 0.0f;
    if (gr >= 0 && gr < 64 && c >= 1 && c <= 64) v = xb[ci * 4096 + gr * 64 + (c - 1)];
    imgp[ci * IMG_CI + lr * IMG_STRIDE + c] = v;
  }
}

// ---------------- Encoder pass A: slab conv + sum/sumsq partials; + weight bf16 prep ----------------
// grid 2048 (512 images x 4 slabs), 256 thr. thread: pr=tid>>5 (2 conv rows 2pr,2pr+1),
// pc=tid&31 (2 conv cols 2pc,2pc+1); rv[2][4][4] hoisted.
__global__ __launch_bounds__(256) void enc_stats_prep(
    const float* __restrict__ x, const float* __restrict__ cw,
    float* __restrict__ bstats,
    const float* __restrict__ wih, const float* __restrict__ whh,
    const float* __restrict__ pw,
    __hip_bfloat16* __restrict__ wihb, __hip_bfloat16* __restrict__ whhb,
    __hip_bfloat16* __restrict__ pwb) {
  {
    const int n1 = 1536 * 256, n2 = 1536 * 512, n3 = 256 * 512;
    int i = blockIdx.x * 256 + threadIdx.x;
    int st = gridDim.x * 256;
    for (int j = i; j < n1 + n2 + n3; j += st) {
      if (j < n1) {
        int r = j >> 8, c = j & 255;
        wihb[j] = __float2bfloat16(wih[r * 258 + c]);
      } else if (j < n1 + n2) {
        int k = j - n1;
        whhb[k] = __float2bfloat16(whh[k]);
      } else {
        int k = j - n1 - n2;
        pwb[k] = __float2bfloat16(pw[k]);
      }
    }
  }

  __shared__ float imgp[2 * IMG_CI];
  __shared__ float reds[4][16], redq[4][16];
  const int tid = threadIdx.x;
  const int b = blockIdx.x >> 2, slab = blockIdx.x & 3;
  const int wv = tid >> 6;
  stage_slab(imgp, x + b * 8192, slab, tid);
  __syncthreads();

  const int pr = tid >> 5;        // conv rows 2pr, 2pr+1 (local)
  const int pc = tid & 31;        // conv cols 2pc, 2pc+1

  float rv[2][4][4];
#pragma unroll
  for (int ci = 0; ci < 2; ++ci)
#pragma unroll
    for (int dy = 0; dy < 4; ++dy)
#pragma unroll
      for (int j = 0; j < 4; ++j)
        rv[ci][dy][j] = imgp[ci * IMG_CI + (2 * pr + dy) * IMG_STRIDE + 2 * pc + j];

  float s[16], q[16];
#pragma unroll
  for (int c = 0; c < 16; ++c) { s[c] = 0.0f; q[c] = 0.0f; }

#pragma unroll
  for (int c4 = 0; c4 < 4; ++c4) {
    float a[4][4];
#pragma unroll
    for (int ch = 0; ch < 4; ++ch)
#pragma unroll
      for (int p = 0; p < 4; ++p) a[ch][p] = 0.0f;
#pragma unroll
    for (int ci = 0; ci < 2; ++ci) {
      float wk[4][9];
#pragma unroll
      for (int ch = 0; ch < 4; ++ch)
#pragma unroll
        for (int k = 0; k < 9; ++k)
          wk[ch][k] = cw[(c4 * 4 + ch) * 18 + ci * 9 + k];
#pragma unroll
      for (int ry = 0; ry < 2; ++ry)
#pragma unroll
        for (int rx = 0; rx < 2; ++rx)
#pragma unroll
          for (int ch = 0; ch < 4; ++ch) {
            float acc = a[ch][ry * 2 + rx];
#pragma unroll
            for (int dy = 0; dy < 3; ++dy) {
              acc = fmaf(wk[ch][dy * 3 + 0], rv[ci][ry + dy][rx + 0], acc);
              acc = fmaf(wk[ch][dy * 3 + 1], rv[ci][ry + dy][rx + 1], acc);
              acc = fmaf(wk[ch][dy * 3 + 2], rv[ci][ry + dy][rx + 2], acc);
            }
            a[ch][ry * 2 + rx] = acc;
          }
    }
#pragma unroll
    for (int ch = 0; ch < 4; ++ch)
#pragma unroll
      for (int p = 0; p < 4; ++p) {
        const float v = a[ch][p];
        s[c4 * 4 + ch] += v;
        q[c4 * 4 + ch] = fmaf(v, v, q[c4 * 4 + ch]);
      }
  }

#pragma unroll
  for (int c = 0; c < 16; ++c) {
    float sv = s[c], qv = q[c];
#pragma unroll
    for (int off = 32; off >= 1; off >>= 1) {
      sv += __shfl_down(sv, off);
      qv += __shfl_down(qv, off);
    }
    if ((tid & 63) == 0) { reds[wv][c] = sv; redq[wv][c] = qv; }
  }
  __syncthreads();
  if (tid < 16)
    bstats[blockIdx.x * 32 + tid] = reds[0][tid] + reds[1][tid] + reds[2][tid] + reds[3][tid];
  else if (tid < 32) {
    int c = tid - 16;
    bstats[blockIdx.x * 32 + tid] = redq[0][c] + redq[1][c] + redq[2][c] + redq[3][c];
  }
}

// reduce 2048 x 32 partials -> 32 stats
__global__ __launch_bounds__(256) void reduce_stats_k(const float* __restrict__ bstats,
                                                      float* __restrict__ stats) {
  __shared__ float acc[8][32];
  const int c = threadIdx.x & 31, part = threadIdx.x >> 5;
  float s = 0;
  for (int i = part; i < 2048; i += 8) s += bstats[i * 32 + c];
  acc[part][c] = s;
  __syncthreads();
  if (threadIdx.x < 32) {
    float t = 0;
#pragma unroll
    for (int p = 0; p < 8; ++p) t += acc[p][threadIdx.x];
    stats[threadIdx.x] = t;
  }
}

// ---------------- Encoder pass B: slab conv + BN + relu + 2x2 maxpool -> pooled partials ----------------
// grid 2048, 256 thr. thread = ONE pool px (8 pool rows x 32 cols per slab).
__global__ __launch_bounds__(256) void enc_pool(const float* __restrict__ x,
                                                const float* __restrict__ cw,
                                                const float* __restrict__ stats,
                                                const float* __restrict__ gamma,
                                                const float* __restrict__ beta,
                                                float* __restrict__ pooledG) {
  __shared__ float imgp[2 * IMG_CI];
  __shared__ float red[4][16];
  __shared__ float statsL[32];
  const int tid = threadIdx.x;
  const int b = blockIdx.x >> 2, slab = blockIdx.x & 3;
  const int wv = tid >> 6;
  stage_slab(imgp, x + b * 8192, slab, tid);
  if (tid < 32) statsL[tid] = stats[tid];
  __syncthreads();

  const float invN = 1.0f / (512.0f * 4096.0f);
  const int pr = tid >> 5;
  const int pc = tid & 31;

  float rv[2][4][4];
#pragma unroll
  for (int ci = 0; ci < 2; ++ci)
#pragma unroll
    for (int dy = 0; dy < 4; ++dy)
#pragma unroll
      for (int j = 0; j < 4; ++j)
        rv[ci][dy][j] = imgp[ci * IMG_CI + (2 * pr + dy) * IMG_STRIDE + 2 * pc + j];

  float psum[16];
#pragma unroll
  for (int c = 0; c < 16; ++c) psum[c] = 0.0f;

#pragma unroll
  for (int c4 = 0; c4 < 4; ++c4) {
    float a[4][4];
#pragma unroll
    for (int ch = 0; ch < 4; ++ch)
#pragma unroll
      for (int p = 0; p < 4; ++p) a[ch][p] = 0.0f;
#pragma unroll
    for (int ci = 0; ci < 2; ++ci) {
      float wk[4][9];
#pragma unroll
      for (int ch = 0; ch < 4; ++ch)
#pragma unroll
        for (int k = 0; k < 9; ++k)
          wk[ch][k] = cw[(c4 * 4 + ch) * 18 + ci * 9 + k];
#pragma unroll
      for (int ry = 0; ry < 2; ++ry)
#pragma unroll
        for (int rx = 0; rx < 2; ++rx)
#pragma unroll
          for (int ch = 0; ch < 4; ++ch) {
            float acc = a[ch][ry * 2 + rx];
#pragma unroll
            for (int dy = 0; dy < 3; ++dy) {
              acc = fmaf(wk[ch][dy * 3 + 0], rv[ci][ry + dy][rx + 0], acc);
              acc = fmaf(wk[ch][dy * 3 + 1], rv[ci][ry + dy][rx + 1], acc);
              acc = fmaf(wk[ch][dy * 3 + 2], rv[ci][ry + dy][rx + 2], acc);
            }
            a[ch][ry * 2 + rx] = acc;
          }
    }
#pragma unroll
    for (int ch = 0; ch < 4; ++ch) {
      const int c = c4 * 4 + ch;
      const float m = statsL[c] * invN;
      const float var = statsL[16 + c] * invN - m * m;
      const float isd = rsqrtf(var + 1e-5f);
      const float sc = gamma[c] * isd;
      const float sh = beta[c] - m * sc;
      const float v0 = fmaxf(fmaf(a[ch][0], sc, sh), 0.0f);
      const float v1 = fmaxf(fmaf(a[ch][1], sc, sh), 0.0f);
      const float v2 = fmaxf(fmaf(a[ch][2], sc, sh), 0.0f);
      const float v3 = fmaxf(fmaf(a[ch][3], sc, sh), 0.0f);
      psum[c] += fmaxf(fmaxf(v0, v1), fmaxf(v2, v3));
    }
  }

#pragma unroll
  for (int c = 0; c < 16; ++c) {
    float v = psum[c];
#pragma unroll
    for (int off = 32; off >= 1; off >>= 1) v += __shfl_down(v, off);
    if ((tid & 63) == 0) red[wv][c] = v;
  }
  __syncthreads();
  if (tid < 16)
    pooledG[blockIdx.x * 16 + tid] = red[0][tid] + red[1][tid] + red[2][tid] + red[3][tid];
}

// ---------------- GRU gates, gate-per-wave: 512 blocks x 384 thr (6 waves) ----------------
// t==0: s(0) computed in-kernel from pooled partials (FC) + written to out slot 0 (cg==0).
__global__ __launch_bounds__(384) void gru_v2(
    const __hip_bfloat16* __restrict__ spb,
    const __hip_bfloat16* __restrict__ hb_in,
    __hip_bfloat16* __restrict__ hb_out,
    const __hip_bfloat16* __restrict__ wihb,   // [1536][256]
    const __hip_bfloat16* __restrict__ whhb,   // [1536][512]
    const float* __restrict__ wih,             // fp32, u-tail cols 256,257
    const float* __restrict__ actions,         // [512][16][2]
    const float* __restrict__ bih, const float* __restrict__ bhh,
    const float* __restrict__ pooledG,         // [2048][16]
    const float* __restrict__ fcw,             // [256][16]
    const float* __restrict__ fcb,             // [256]
    float* __restrict__ out,
    int t) {
  __shared__ __hip_bfloat16 sF[8 * 64 * 8];    // 8KB:  s A-frags, frag-order
  __shared__ __hip_bfloat16 hF[16 * 64 * 8];   // 16KB: h A-frags, frag-order
  __shared__ float accL[4][2][256];            // 8KB (t=0: first 256 f reused as avg)
  const int tid = threadIdx.x;
  const int w = tid / 64, lane = tid & 63;
  const int l15 = lane & 15, hi = lane >> 4;
  const int cg = blockIdx.x, band = blockIdx.y;
  const int row0 = band * 16;
  const int ct = w & 1, g = w >> 1;

  if (t == 0) {
    float* avgF = &accL[0][0][0];  // 256 floats: avg pooled per (r, k)
    if (tid < 256) {
      const int r = tid >> 4, k = tid & 15;
      const int img = row0 + r;
      const float v = pooledG[(img * 4 + 0) * 16 + k] + pooledG[(img * 4 + 1) * 16 + k] +
                      pooledG[(img * 4 + 2) * 16 + k] + pooledG[(img * 4 + 3) * 16 + k];
      avgF[r * 16 + k] = v * (1.0f / 1024.0f);
    }
    __syncthreads();
    for (int i = tid; i < 4096; i += 384) {
      const int kk = i >> 9, rem = i & 511, ln = rem >> 3, e = rem & 7;
      const int r = ln & 15;
      const int col = kk * 32 + (ln >> 4) * 8 + e;
      float v = fcb[col];
#pragma unroll
      for (int k = 0; k < 16; ++k) v = fmaf(avgF[r * 16 + k], fcw[col * 16 + k], v);
      sF[i] = __float2bfloat16(v);
      if (cg == 0) out[((size_t)(row0 + r) * TT + 0) * 256 + col] = v;
    }
  } else {
    for (int i = tid; i < 512; i += 384) {
      int kk = i >> 6, ln = i & 63;
      *(bf16x8*)(sF + i * 8) =
          *(const bf16x8*)(spb + (row0 + (ln & 15)) * 256 + kk * 32 + (ln >> 4) * 8);
    }
    for (int i = tid; i < 1024; i += 384) {
      int kk = i >> 6, ln = i & 63;
      *(bf16x8*)(hF + i * 8) =
          *(const bf16x8*)(hb_in + (row0 + (ln & 15)) * 512 + kk * 32 + (ln >> 4) * 8);
    }
  }
  __syncthreads();

  const int cj = cg * 32 + ct * 16;
  f32x4 accS = {0.f, 0.f, 0.f, 0.f}, accH = accS;
  {
    const __hip_bfloat16* B = wihb + (g * 512 + cj + l15) * 256 + hi * 8;
#pragma unroll
    for (int kk = 0; kk < 8; ++kk) {
      bf16x8 a = *(const bf16x8*)(sF + (kk * 64 + lane) * 8);
      accS = __builtin_amdgcn_mfma_f32_16x16x32_bf16(a, *(const bf16x8*)(B + kk * 32),
                                                     accS, 0, 0, 0);
    }
  }
  if (t > 0) {
    const __hip_bfloat16* B = whhb + (g * 512 + cj + l15) * 512 + hi * 8;
#pragma unroll
    for (int kk = 0; kk < 16; ++kk) {
      bf16x8 a = *(const bf16x8*)(hF + (kk * 64 + lane) * 8);
      accH = __builtin_amdgcn_mfma_f32_16x16x32_bf16(a, *(const bf16x8*)(B + kk * 32),
                                                     accH, 0, 0, 0);
    }
  }
  __syncthreads();  // t=0: avgF (accL alias) fully read before accL writes
  if (g < 2) {
#pragma unroll
    for (int i = 0; i < 4; ++i)
      accL[g][ct][(hi * 4 + i) * 16 + l15] = accS[i] + accH[i];
  } else {
#pragma unroll
    for (int i = 0; i < 4; ++i) {
      accL[2][ct][(hi * 4 + i) * 16 + l15] = accS[i];
      accL[3][ct][(hi * 4 + i) * 16 + l15] = accH[i];
    }
  }
  __syncthreads();

  if (w < 2) {
    f32x4 vR = *(const f32x4*)&accL[0][w][lane * 4];
    f32x4 vZ = *(const f32x4*)&accL[1][w][lane * 4];
    f32x4 vXN = *(const f32x4*)&accL[2][w][lane * 4];
    f32x4 vHN = *(const f32x4*)&accL[3][w][lane * 4];
    const int r = lane >> 2;
    const int row = row0 + r;
    const float u0 = actions[row * 32 + t * 2 + 0];
    const float u1 = actions[row * 32 + t * 2 + 1];
#pragma unroll
    for (int j = 0; j < 4; ++j) {
      const int c = (lane & 3) * 4 + j;
      const int col = cg * 32 + w * 16 + c;
      const float br = bih[col] + bhh[col];
      const float bz = bih[512 + col] + bhh[512 + col];
      const float bxn = bih[1024 + col];
      const float bhn = bhh[1024 + col];
      const float wur = wih[col * 258 + 256], wvr = wih[col * 258 + 257];
      const float wuz = wih[(512 + col) * 258 + 256], wvz = wih[(512 + col) * 258 + 257];
      const float wun = wih[(1024 + col) * 258 + 256], wvn = wih[(1024 + col) * 258 + 257];
      const float gr = vR[j] + br + u0 * wur + u1 * wvr;
      const float gz = vZ[j] + bz + u0 * wuz + u1 * wvz;
      const float gxn = vXN[j] + bxn + u0 * wun + u1 * wvn;
      const float ghn = vHN[j] + bhn;
      const float rg = 1.0f / (1.0f + __expf(-gr));
      const float zg = 1.0f / (1.0f + __expf(-gz));
      float xn = gxn + rg * ghn;
      xn = fminf(fmaxf(xn, -15.0f), 15.0f);
      const float e = __expf(2.0f * xn);
      const float ng = (e - 1.0f) / (e + 1.0f);
      const float hp = (t > 0) ? (float)hb_in[row * 512 + col] : 0.0f;
      const float hnv = (1.0f - zg) * ng + zg * hp;
      hb_out[row * 512 + col] = __float2bfloat16(hnv);
    }
  }
}

// ---------------- pred, split-K-4: 512 blocks x 256 thr (4 waves) ----------------
__global__ __launch_bounds__(256) void pred_v2(
    const __hip_bfloat16* __restrict__ hb,
    const __hip_bfloat16* __restrict__ pwb,    // [256][512]
    const float* __restrict__ pb,
    float* __restrict__ out,
    __hip_bfloat16* __restrict__ spb,
    int slot) {
  __shared__ float accL[4][256];
  const int tid = threadIdx.x;
  const int w = tid >> 6, lane = tid & 63;
  const int l15 = lane & 15, hi = lane >> 4;
  const int pcg = blockIdx.x, band = blockIdx.y;
  const int row0 = band * 16, pc0 = pcg * 16;
  f32x4 acc = {0.f, 0.f, 0.f, 0.f};
  const __hip_bfloat16* A = hb + (row0 + l15) * 512 + w * 128 + hi * 8;
  const __hip_bfloat16* B = pwb + (pc0 + l15) * 512 + w * 128 + hi * 8;
#pragma unroll
  for (int kk = 0; kk < 4; ++kk)
    acc = __builtin_amdgcn_mfma_f32_16x16x32_bf16(*(const bf16x8*)(A + kk * 32),
                                                  *(const bf16x8*)(B + kk * 32),
                                                  acc, 0, 0, 0);
#pragma unroll
  for (int i = 0; i < 4; ++i) accL[w][(hi * 4 + i) * 16 + l15] = acc[i];
  __syncthreads();
  if (w == 0) {
    f32x4 p0 = *(const f32x4*)&accL[0][lane * 4];
    f32x4 p1 = *(const f32x4*)&accL[1][lane * 4];
    f32x4 p2 = *(const f32x4*)&accL[2][lane * 4];
    f32x4 p3 = *(const f32x4*)&accL[3][lane * 4];
    const int r = lane >> 2;
    const int row = row0 + r;
    float4 ov;
    float* po = &ov.x;
#pragma unroll
    for (int j = 0; j < 4; ++j) {
      const int c = (lane & 3) * 4 + j;
      const int col = pc0 + c;
      float v = p0[j] + p1[j] + p2[j] + p3[j] + pb[col];
      v = fmaxf(v, 0.0f);
      po[j] = v;
      spb[row * 256 + col] = __float2bfloat16(v);
    }
    *(float4*)(out + ((size_t)row * TT + slot) * 256 + pc0 + (lane & 3) * 4) = ov;
  }
}

extern "C" void kernel_launch(void* const* d_in, const int* in_sizes, int n_in,
                              void* d_out, int out_size, void* d_ws, size_t ws_size,
                              hipStream_t stream) {
  const float* x       = (const float*)d_in[0];
  const float* actions = (const float*)d_in[1];
  const float* cw      = (const float*)d_in[2];
  const float* gamma   = (const float*)d_in[3];
  const float* beta    = (const float*)d_in[4];
  const float* fcw     = (const float*)d_in[5];
  const float* fcb     = (const float*)d_in[6];
  const float* wih     = (const float*)d_in[7];
  const float* whh     = (const float*)d_in[8];
  const float* bih     = (const float*)d_in[9];
  const float* bhh     = (const float*)d_in[10];
  const float* pw      = (const float*)d_in[11];
  const float* pb      = (const float*)d_in[12];
  float* out = (float*)d_out;
  float* ws  = (float*)d_ws;

  float* bstats  = ws + OFF_BSTATS;
  float* stats   = ws + OFF_STATS;
  float* pooledG = ws + OFF_POOLED;
  __hip_bfloat16* spb  = (__hip_bfloat16*)(ws + OFF_SPB);
  __hip_bfloat16* pwb  = (__hip_bfloat16*)(ws + OFF_PWB);
  __hip_bfloat16* wihb = (__hip_bfloat16*)(ws + OFF_WIHB);
  __hip_bfloat16* whhb = (__hip_bfloat16*)(ws + OFF_WHHB);
  __hip_bfloat16* hb0  = (__hip_bfloat16*)(ws + OFF_HB);
  __hip_bfloat16* hb1  = hb0 + 512 * 512;

  enc_stats_prep<<<dim3(2048), dim3(256), 0, stream>>>(x, cw, bstats, wih, whh, pw,
                                                       wihb, whhb, pwb);
  reduce_stats_k<<<dim3(1), dim3(256), 0, stream>>>(bstats, stats);
  enc_pool<<<dim3(2048), dim3(256), 0, stream>>>(x, cw, stats, gamma, beta, pooledG);
  for (int t = 0; t < TM1; ++t) {
    __hip_bfloat16* hbi = (t & 1) ? hb1 : hb0;
    __hip_bfloat16* hbo = (t & 1) ? hb0 : hb1;
    gru_v2<<<dim3(16, 32), dim3(384), 0, stream>>>(spb, hbi, hbo, wihb, whhb,
                                                   wih, actions, bih, bhh,
                                                   pooledG, fcw, fcb, out, t);
    pred_v2<<<dim3(16, 32), dim3(256), 0, stream>>>(hbo, pwb, pb, out, spb, t + 1);
  }
}

// Round 13
// 344.688 us; speedup vs baseline: 1.2018x; 1.2018x over previous
//
#include <hip/hip_runtime.h>
#include <hip/hip_bf16.h>
#include <math.h>

#define TM1 16
#define TT 17

typedef __attribute__((ext_vector_type(8))) __bf16 bf16x8;
typedef __attribute__((ext_vector_type(4))) float f32x4;

// ---------------- workspace layout (float units) ----------------
#define OFF_BSTATS 0          // 32*2048 = 65536 (TRANSPOSED: [stat][block])
#define OFF_STATS  65536      // 32
#define OFF_POOLED 65568      // 2048*16 = 32768
#define OFF_BCOL   98336      // 512*12 = 6144 (packed epilogue constants)
#define OFF_SPB    104480     // 512*256 bf16 = 65536 f
#define OFF_PWB    170016     // 256*512 bf16 = 65536 f
#define OFF_WIHB   235552     // 1536*256 bf16 = 196608 f
#define OFF_WHHB   432160     // 1536*512 bf16 = 393216 f
#define OFF_HB     825376     // 2 x 512*512 bf16 = 262144 f
// total 1087520 floats ~= 4.35 MB

#define IMG_STRIDE 67
#define SLAB_ROWS 18
#define IMG_CI (SLAB_ROWS * IMG_STRIDE)   // 1206

// Slab staging shared by both passes: block = (image b, slab s of 4).
__device__ __forceinline__ void stage_slab(float* __restrict__ imgp,
                                           const float* __restrict__ xb, int slab, int tid) {
  for (int i = tid; i < 2 * SLAB_ROWS * 66; i += 256) {
    const int ci = i / (SLAB_ROWS * 66);
    const int rem = i - ci * (SLAB_ROWS * 66);
    const int lr = rem / 66, c = rem - lr * 66;
    const int gr = slab * 16 - 1 + lr;
    float v = 0.0f;
    if (gr >= 0 && gr < 64 && c >= 1 && c <= 64) v = xb[ci * 4096 + gr * 64 + (c - 1)];
    imgp[ci * IMG_CI + lr * IMG_STRIDE + c] = v;
  }
}

// ---------------- Encoder pass A: slab conv + sum/sumsq partials; + weight/bcol prep ----------------
__global__ __launch_bounds__(256) void enc_stats_prep(
    const float* __restrict__ x, const float* __restrict__ cw,
    float* __restrict__ bstats,
    const float* __restrict__ wih, const float* __restrict__ whh,
    const float* __restrict__ pw,
    const float* __restrict__ bih, const float* __restrict__ bhh,
    __hip_bfloat16* __restrict__ wihb, __hip_bfloat16* __restrict__ whhb,
    __hip_bfloat16* __restrict__ pwb, float* __restrict__ bcol) {
  {
    const int n1 = 1536 * 256, n2 = 1536 * 512, n3 = 256 * 512, n4 = 512 * 12;
    int i = blockIdx.x * 256 + threadIdx.x;
    int st = gridDim.x * 256;
    for (int j = i; j < n1 + n2 + n3 + n4; j += st) {
      if (j < n1) {
        int r = j >> 8, c = j & 255;
        wihb[j] = __float2bfloat16(wih[r * 258 + c]);
      } else if (j < n1 + n2) {
        int k = j - n1;
        whhb[k] = __float2bfloat16(whh[k]);
      } else if (j < n1 + n2 + n3) {
        int k = j - n1 - n2;
        pwb[k] = __float2bfloat16(pw[k]);
      } else {
        int k = j - n1 - n2 - n3;
        int col = k / 12, e = k - col * 12;
        float v = 0.0f;
        switch (e) {
          case 0: v = bih[col] + bhh[col]; break;
          case 1: v = bih[512 + col] + bhh[512 + col]; break;
          case 2: v = bih[1024 + col]; break;
          case 3: v = bhh[1024 + col]; break;
          case 4: v = wih[col * 258 + 256]; break;
          case 5: v = wih[col * 258 + 257]; break;
          case 6: v = wih[(512 + col) * 258 + 256]; break;
          case 7: v = wih[(512 + col) * 258 + 257]; break;
          case 8: v = wih[(1024 + col) * 258 + 256]; break;
          case 9: v = wih[(1024 + col) * 258 + 257]; break;
          default: v = 0.0f; break;
        }
        bcol[k] = v;
      }
    }
  }

  __shared__ float imgp[2 * IMG_CI];
  __shared__ float reds[4][16], redq[4][16];
  const int tid = threadIdx.x;
  const int b = blockIdx.x >> 2, slab = blockIdx.x & 3;
  const int wv = tid >> 6;
  stage_slab(imgp, x + b * 8192, slab, tid);
  __syncthreads();

  const int pr = tid >> 5;
  const int pc = tid & 31;

  float rv[2][4][4];
#pragma unroll
  for (int ci = 0; ci < 2; ++ci)
#pragma unroll
    for (int dy = 0; dy < 4; ++dy)
#pragma unroll
      for (int j = 0; j < 4; ++j)
        rv[ci][dy][j] = imgp[ci * IMG_CI + (2 * pr + dy) * IMG_STRIDE + 2 * pc + j];

  float s[16], q[16];
#pragma unroll
  for (int c = 0; c < 16; ++c) { s[c] = 0.0f; q[c] = 0.0f; }

#pragma unroll
  for (int c4 = 0; c4 < 4; ++c4) {
    float a[4][4];
#pragma unroll
    for (int ch = 0; ch < 4; ++ch)
#pragma unroll
      for (int p = 0; p < 4; ++p) a[ch][p] = 0.0f;
#pragma unroll
    for (int ci = 0; ci < 2; ++ci) {
      float wk[4][9];
#pragma unroll
      for (int ch = 0; ch < 4; ++ch)
#pragma unroll
        for (int k = 0; k < 9; ++k)
          wk[ch][k] = cw[(c4 * 4 + ch) * 18 + ci * 9 + k];
#pragma unroll
      for (int ry = 0; ry < 2; ++ry)
#pragma unroll
        for (int rx = 0; rx < 2; ++rx)
#pragma unroll
          for (int ch = 0; ch < 4; ++ch) {
            float acc = a[ch][ry * 2 + rx];
#pragma unroll
            for (int dy = 0; dy < 3; ++dy) {
              acc = fmaf(wk[ch][dy * 3 + 0], rv[ci][ry + dy][rx + 0], acc);
              acc = fmaf(wk[ch][dy * 3 + 1], rv[ci][ry + dy][rx + 1], acc);
              acc = fmaf(wk[ch][dy * 3 + 2], rv[ci][ry + dy][rx + 2], acc);
            }
            a[ch][ry * 2 + rx] = acc;
          }
    }
#pragma unroll
    for (int ch = 0; ch < 4; ++ch)
#pragma unroll
      for (int p = 0; p < 4; ++p) {
        const float v = a[ch][p];
        s[c4 * 4 + ch] += v;
        q[c4 * 4 + ch] = fmaf(v, v, q[c4 * 4 + ch]);
      }
  }

#pragma unroll
  for (int c = 0; c < 16; ++c) {
    float sv = s[c], qv = q[c];
#pragma unroll
    for (int off = 32; off >= 1; off >>= 1) {
      sv += __shfl_down(sv, off);
      qv += __shfl_down(qv, off);
    }
    if ((tid & 63) == 0) { reds[wv][c] = sv; redq[wv][c] = qv; }
  }
  __syncthreads();
  // TRANSPOSED partial store: bstats[stat][block]
  if (tid < 16)
    bstats[tid * 2048 + blockIdx.x] =
        reds[0][tid] + reds[1][tid] + reds[2][tid] + reds[3][tid];
  else if (tid < 32) {
    int c = tid - 16;
    bstats[tid * 2048 + blockIdx.x] =
        redq[0][c] + redq[1][c] + redq[2][c] + redq[3][c];
  }
}

// reduce: 32 blocks; block c sums contiguous bstats[c][0..2048) -> stats[c]
__global__ __launch_bounds__(256) void reduce_stats_k(const float* __restrict__ bstats,
                                                      float* __restrict__ stats) {
  __shared__ float acc[4];
  const int c = blockIdx.x, tid = threadIdx.x;
  const float4 v4 = *(const float4*)(bstats + c * 2048 + tid * 8);
  const float4 w4 = *(const float4*)(bstats + c * 2048 + tid * 8 + 4);
  float v = v4.x + v4.y + v4.z + v4.w + w4.x + w4.y + w4.z + w4.w;
#pragma unroll
  for (int off = 32; off >= 1; off >>= 1) v += __shfl_down(v, off);
  if ((tid & 63) == 0) acc[tid >> 6] = v;
  __syncthreads();
  if (tid == 0) stats[c] = acc[0] + acc[1] + acc[2] + acc[3];
}

// ---------------- Encoder pass B: slab conv + BN + relu + 2x2 maxpool -> pooled partials ----------------
__global__ __launch_bounds__(256) void enc_pool(const float* __restrict__ x,
                                                const float* __restrict__ cw,
                                                const float* __restrict__ stats,
                                                const float* __restrict__ gamma,
                                                const float* __restrict__ beta,
                                                float* __restrict__ pooledG) {
  __shared__ float imgp[2 * IMG_CI];
  __shared__ float red[4][16];
  __shared__ float statsL[32];
  const int tid = threadIdx.x;
  const int b = blockIdx.x >> 2, slab = blockIdx.x & 3;
  const int wv = tid >> 6;
  stage_slab(imgp, x + b * 8192, slab, tid);
  if (tid < 32) statsL[tid] = stats[tid];
  __syncthreads();

  const float invN = 1.0f / (512.0f * 4096.0f);
  const int pr = tid >> 5;
  const int pc = tid & 31;

  float rv[2][4][4];
#pragma unroll
  for (int ci = 0; ci < 2; ++ci)
#pragma unroll
    for (int dy = 0; dy < 4; ++dy)
#pragma unroll
      for (int j = 0; j < 4; ++j)
        rv[ci][dy][j] = imgp[ci * IMG_CI + (2 * pr + dy) * IMG_STRIDE + 2 * pc + j];

  float psum[16];
#pragma unroll
  for (int c = 0; c < 16; ++c) psum[c] = 0.0f;

#pragma unroll
  for (int c4 = 0; c4 < 4; ++c4) {
    float a[4][4];
#pragma unroll
    for (int ch = 0; ch < 4; ++ch)
#pragma unroll
      for (int p = 0; p < 4; ++p) a[ch][p] = 0.0f;
#pragma unroll
    for (int ci = 0; ci < 2; ++ci) {
      float wk[4][9];
#pragma unroll
      for (int ch = 0; ch < 4; ++ch)
#pragma unroll
        for (int k = 0; k < 9; ++k)
          wk[ch][k] = cw[(c4 * 4 + ch) * 18 + ci * 9 + k];
#pragma unroll
      for (int ry = 0; ry < 2; ++ry)
#pragma unroll
        for (int rx = 0; rx < 2; ++rx)
#pragma unroll
          for (int ch = 0; ch < 4; ++ch) {
            float acc = a[ch][ry * 2 + rx];
#pragma unroll
            for (int dy = 0; dy < 3; ++dy) {
              acc = fmaf(wk[ch][dy * 3 + 0], rv[ci][ry + dy][rx + 0], acc);
              acc = fmaf(wk[ch][dy * 3 + 1], rv[ci][ry + dy][rx + 1], acc);
              acc = fmaf(wk[ch][dy * 3 + 2], rv[ci][ry + dy][rx + 2], acc);
            }
            a[ch][ry * 2 + rx] = acc;
          }
    }
#pragma unroll
    for (int ch = 0; ch < 4; ++ch) {
      const int c = c4 * 4 + ch;
      const float m = statsL[c] * invN;
      const float var = statsL[16 + c] * invN - m * m;
      const float isd = rsqrtf(var + 1e-5f);
      const float sc = gamma[c] * isd;
      const float sh = beta[c] - m * sc;
      const float v0 = fmaxf(fmaf(a[ch][0], sc, sh), 0.0f);
      const float v1 = fmaxf(fmaf(a[ch][1], sc, sh), 0.0f);
      const float v2 = fmaxf(fmaf(a[ch][2], sc, sh), 0.0f);
      const float v3 = fmaxf(fmaf(a[ch][3], sc, sh), 0.0f);
      psum[c] += fmaxf(fmaxf(v0, v1), fmaxf(v2, v3));
    }
  }

#pragma unroll
  for (int c = 0; c < 16; ++c) {
    float v = psum[c];
#pragma unroll
    for (int off = 32; off >= 1; off >>= 1) v += __shfl_down(v, off);
    if ((tid & 63) == 0) red[wv][c] = v;
  }
  __syncthreads();
  if (tid < 16)
    pooledG[blockIdx.x * 16 + tid] = red[0][tid] + red[1][tid] + red[2][tid] + red[3][tid];
}

// ---------------- GRU gates, gate-per-wave: 512 blocks x 384 thr (6 waves) ----------------
__global__ __launch_bounds__(384) void gru_v2(
    const __hip_bfloat16* __restrict__ spb,
    const __hip_bfloat16* __restrict__ hb_in,
    __hip_bfloat16* __restrict__ hb_out,
    const __hip_bfloat16* __restrict__ wihb,   // [1536][256]
    const __hip_bfloat16* __restrict__ whhb,   // [1536][512]
    const float* __restrict__ bcol,            // [512][12] packed epilogue constants
    const float* __restrict__ actions,         // [512][16][2]
    const float* __restrict__ pooledG,         // [2048][16]
    const float* __restrict__ fcw,             // [256][16]
    const float* __restrict__ fcb,             // [256]
    float* __restrict__ out,
    int t) {
  __shared__ __hip_bfloat16 sF[8 * 64 * 8];    // 8KB:  s A-frags, frag-order
  __shared__ __hip_bfloat16 hF[16 * 64 * 8];   // 16KB: h A-frags, frag-order
  __shared__ float accL[4][2][256];            // 8KB (t=0: first 256 f reused as avg)
  const int tid = threadIdx.x;
  const int w = tid / 64, lane = tid & 63;
  const int l15 = lane & 15, hi = lane >> 4;
  const int cg = blockIdx.x, band = blockIdx.y;
  const int row0 = band * 16;
  const int ct = w & 1, g = w >> 1;

  if (t == 0) {
    float* avgF = &accL[0][0][0];
    if (tid < 256) {
      const int r = tid >> 4, k = tid & 15;
      const int img = row0 + r;
      const float v = pooledG[(img * 4 + 0) * 16 + k] + pooledG[(img * 4 + 1) * 16 + k] +
                      pooledG[(img * 4 + 2) * 16 + k] + pooledG[(img * 4 + 3) * 16 + k];
      avgF[r * 16 + k] = v * (1.0f / 1024.0f);
    }
    __syncthreads();
    for (int i = tid; i < 4096; i += 384) {
      const int kk = i >> 9, rem = i & 511, ln = rem >> 3, e = rem & 7;
      const int r = ln & 15;
      const int col = kk * 32 + (ln >> 4) * 8 + e;
      float v = fcb[col];
#pragma unroll
      for (int k = 0; k < 16; ++k) v = fmaf(avgF[r * 16 + k], fcw[col * 16 + k], v);
      sF[i] = __float2bfloat16(v);
      if (cg == 0) out[((size_t)(row0 + r) * TT + 0) * 256 + col] = v;
    }
  } else {
    for (int i = tid; i < 512; i += 384) {
      int kk = i >> 6, ln = i & 63;
      *(bf16x8*)(sF + i * 8) =
          *(const bf16x8*)(spb + (row0 + (ln & 15)) * 256 + kk * 32 + (ln >> 4) * 8);
    }
    for (int i = tid; i < 1024; i += 384) {
      int kk = i >> 6, ln = i & 63;
      *(bf16x8*)(hF + i * 8) =
          *(const bf16x8*)(hb_in + (row0 + (ln & 15)) * 512 + kk * 32 + (ln >> 4) * 8);
    }
  }
  __syncthreads();

  const int cj = cg * 32 + ct * 16;
  f32x4 accS = {0.f, 0.f, 0.f, 0.f}, accH = accS;
  {
    const __hip_bfloat16* B = wihb + (g * 512 + cj + l15) * 256 + hi * 8;
#pragma unroll
    for (int kk = 0; kk < 8; ++kk) {
      bf16x8 a = *(const bf16x8*)(sF + (kk * 64 + lane) * 8);
      accS = __builtin_amdgcn_mfma_f32_16x16x32_bf16(a, *(const bf16x8*)(B + kk * 32),
                                                     accS, 0, 0, 0);
    }
  }
  if (t > 0) {
    const __hip_bfloat16* B = whhb + (g * 512 + cj + l15) * 512 + hi * 8;
#pragma unroll
    for (int kk = 0; kk < 16; ++kk) {
      bf16x8 a = *(const bf16x8*)(hF + (kk * 64 + lane) * 8);
      accH = __builtin_amdgcn_mfma_f32_16x16x32_bf16(a, *(const bf16x8*)(B + kk * 32),
                                                     accH, 0, 0, 0);
    }
  }
  __syncthreads();
  if (g < 2) {
#pragma unroll
    for (int i = 0; i < 4; ++i)
      accL[g][ct][(hi * 4 + i) * 16 + l15] = accS[i] + accH[i];
  } else {
#pragma unroll
    for (int i = 0; i < 4; ++i) {
      accL[2][ct][(hi * 4 + i) * 16 + l15] = accS[i];
      accL[3][ct][(hi * 4 + i) * 16 + l15] = accH[i];
    }
  }
  __syncthreads();

  if (w < 2) {
    f32x4 vR = *(const f32x4*)&accL[0][w][lane * 4];
    f32x4 vZ = *(const f32x4*)&accL[1][w][lane * 4];
    f32x4 vXN = *(const f32x4*)&accL[2][w][lane * 4];
    f32x4 vHN = *(const f32x4*)&accL[3][w][lane * 4];
    const int r = lane >> 2;
    const int row = row0 + r;
    const float u0 = actions[row * 32 + t * 2 + 0];
    const float u1 = actions[row * 32 + t * 2 + 1];
#pragma unroll
    for (int j = 0; j < 4; ++j) {
      const int c = (lane & 3) * 4 + j;
      const int col = cg * 32 + w * 16 + c;
      const float4 b0 = *(const float4*)(bcol + col * 12);      // br,bz,bxn,bhn
      const float4 b1 = *(const float4*)(bcol + col * 12 + 4);  // wur,wvr,wuz,wvz
      const float4 b2 = *(const float4*)(bcol + col * 12 + 8);  // wun,wvn,-,-
      const float gr = vR[j] + b0.x + u0 * b1.x + u1 * b1.y;
      const float gz = vZ[j] + b0.y + u0 * b1.z + u1 * b1.w;
      const float gxn = vXN[j] + b0.z + u0 * b2.x + u1 * b2.y;
      const float ghn = vHN[j] + b0.w;
      const float rg = 1.0f / (1.0f + __expf(-gr));
      const float zg = 1.0f / (1.0f + __expf(-gz));
      float xn = gxn + rg * ghn;
      xn = fminf(fmaxf(xn, -15.0f), 15.0f);
      const float e = __expf(2.0f * xn);
      const float ng = (e - 1.0f) / (e + 1.0f);
      const float hp = (t > 0) ? (float)hb_in[row * 512 + col] : 0.0f;
      const float hnv = (1.0f - zg) * ng + zg * hp;
      hb_out[row * 512 + col] = __float2bfloat16(hnv);
    }
  }
}

// ---------------- pred, split-K-4: 512 blocks x 256 thr (4 waves) ----------------
__global__ __launch_bounds__(256) void pred_v2(
    const __hip_bfloat16* __restrict__ hb,
    const __hip_bfloat16* __restrict__ pwb,    // [256][512]
    const float* __restrict__ pb,
    float* __restrict__ out,
    __hip_bfloat16* __restrict__ spb,
    int slot) {
  __shared__ float accL[4][256];
  const int tid = threadIdx.x;
  const int w = tid >> 6, lane = tid & 63;
  const int l15 = lane & 15, hi = lane >> 4;
  const int pcg = blockIdx.x, band = blockIdx.y;
  const int row0 = band * 16, pc0 = pcg * 16;
  f32x4 acc = {0.f, 0.f, 0.f, 0.f};
  const __hip_bfloat16* A = hb + (row0 + l15) * 512 + w * 128 + hi * 8;
  const __hip_bfloat16* B = pwb + (pc0 + l15) * 512 + w * 128 + hi * 8;
#pragma unroll
  for (int kk = 0; kk < 4; ++kk)
    acc = __builtin_amdgcn_mfma_f32_16x16x32_bf16(*(const bf16x8*)(A + kk * 32),
                                                  *(const bf16x8*)(B + kk * 32),
                                                  acc, 0, 0, 0);
#pragma unroll
  for (int i = 0; i < 4; ++i) accL[w][(hi * 4 + i) * 16 + l15] = acc[i];
  __syncthreads();
  if (w == 0) {
    f32x4 p0 = *(const f32x4*)&accL[0][lane * 4];
    f32x4 p1 = *(const f32x4*)&accL[1][lane * 4];
    f32x4 p2 = *(const f32x4*)&accL[2][lane * 4];
    f32x4 p3 = *(const f32x4*)&accL[3][lane * 4];
    const int r = lane >> 2;
    const int row = row0 + r;
    float4 ov;
    float* po = &ov.x;
#pragma unroll
    for (int j = 0; j < 4; ++j) {
      const int c = (lane & 3) * 4 + j;
      const int col = pc0 + c;
      float v = p0[j] + p1[j] + p2[j] + p3[j] + pb[col];
      v = fmaxf(v, 0.0f);
      po[j] = v;
      spb[row * 256 + col] = __float2bfloat16(v);
    }
    *(float4*)(out + ((size_t)row * TT + slot) * 256 + pc0 + (lane & 3) * 4) = ov;
  }
}

extern "C" void kernel_launch(void* const* d_in, const int* in_sizes, int n_in,
                              void* d_out, int out_size, void* d_ws, size_t ws_size,
                              hipStream_t stream) {
  const float* x       = (const float*)d_in[0];
  const float* actions = (const float*)d_in[1];
  const float* cw      = (const float*)d_in[2];
  const float* gamma   = (const float*)d_in[3];
  const float* beta    = (const float*)d_in[4];
  const float* fcw     = (const float*)d_in[5];
  const float* fcb     = (const float*)d_in[6];
  const float* wih     = (const float*)d_in[7];
  const float* whh     = (const float*)d_in[8];
  const float* bih     = (const float*)d_in[9];
  const float* bhh     = (const float*)d_in[10];
  const float* pw      = (const float*)d_in[11];
  const float* pb      = (const float*)d_in[12];
  float* out = (float*)d_out;
  float* ws  = (float*)d_ws;

  float* bstats  = ws + OFF_BSTATS;
  float* stats   = ws + OFF_STATS;
  float* pooledG = ws + OFF_POOLED;
  float* bcol    = ws + OFF_BCOL;
  __hip_bfloat16* spb  = (__hip_bfloat16*)(ws + OFF_SPB);
  __hip_bfloat16* pwb  = (__hip_bfloat16*)(ws + OFF_PWB);
  __hip_bfloat16* wihb = (__hip_bfloat16*)(ws + OFF_WIHB);
  __hip_bfloat16* whhb = (__hip_bfloat16*)(ws + OFF_WHHB);
  __hip_bfloat16* hb0  = (__hip_bfloat16*)(ws + OFF_HB);
  __hip_bfloat16* hb1  = hb0 + 512 * 512;

  enc_stats_prep<<<dim3(2048), dim3(256), 0, stream>>>(x, cw, bstats, wih, whh, pw,
                                                       bih, bhh, wihb, whhb, pwb, bcol);
  reduce_stats_k<<<dim3(32), dim3(256), 0, stream>>>(bstats, stats);
  enc_pool<<<dim3(2048), dim3(256), 0, stream>>>(x, cw, stats, gamma, beta, pooledG);
  for (int t = 0; t < TM1; ++t) {
    __hip_bfloat16* hbi = (t & 1) ? hb1 : hb0;
    __hip_bfloat16* hbo = (t & 1) ? hb0 : hb1;
    gru_v2<<<dim3(16, 32), dim3(384), 0, stream>>>(spb, hbi, hbo, wihb, whhb,
                                                   bcol, actions, pooledG, fcw, fcb,
                                                   out, t);
    pred_v2<<<dim3(16, 32), dim3(256), 0, stream>>>(hbo, pwb, pb, out, spb, t + 1);
  }
}

// Round 14
// 335.612 us; speedup vs baseline: 1.2343x; 1.0270x over previous
//
#include <hip/hip_runtime.h>
#include <hip/hip_bf16.h>
#include <math.h>

#define TM1 16
#define TT 17

typedef __attribute__((ext_vector_type(8))) __bf16 bf16x8;
typedef __attribute__((ext_vector_type(4))) float f32x4;

// ---------------- workspace layout (float units) ----------------
#define OFF_BSTATS 0          // 32*2048 = 65536 (TRANSPOSED: [stat][block])
#define OFF_STATS  65536      // 32
#define OFF_POOLED 65568      // 2048*16 = 32768
#define OFF_BCOL   98336      // 512*12 = 6144 (packed epilogue constants)
#define OFF_SPB    104480     // 512*256 bf16 = 65536 f
#define OFF_PWB    170016     // 256*512 bf16 = 65536 f
#define OFF_WIHB   235552     // 1536*256 bf16 = 196608 f
#define OFF_WHHB   432160     // 1536*512 bf16 = 393216 f
#define OFF_HB     825376     // 2 x 512*512 bf16 = 262144 f
// total 1087520 floats ~= 4.35 MB

#define IMG_STRIDE 67
#define SLAB_ROWS 18
#define IMG_CI (SLAB_ROWS * IMG_STRIDE)   // 1206

// Stage one 18-row slab (1-row halo top/bottom, 1-col halo left/right) as bf16.
__device__ __forceinline__ void stage_slab_bf16(__hip_bfloat16* __restrict__ imgp,
                                                const float* __restrict__ xb, int slab,
                                                int tid) {
  for (int i = tid; i < 2 * SLAB_ROWS * 66; i += 256) {
    const int ci = i / (SLAB_ROWS * 66);
    const int rem = i - ci * (SLAB_ROWS * 66);
    const int lr = rem / 66, c = rem - lr * 66;
    const int gr = slab * 16 - 1 + lr;
    float v = 0.0f;
    if (gr >= 0 && gr < 64 && c >= 1 && c <= 64) v = xb[ci * 4096 + gr * 64 + (c - 1)];
    imgp[ci * IMG_CI + lr * IMG_STRIDE + c] = __float2bfloat16(v);
  }
}

// Per-lane im2col k-offsets: k = hi*8+j -> (ci,dy,dx); k>=18 invalid (zero).
__device__ __forceinline__ void make_k_offsets(int hi, int* off, int* val) {
#pragma unroll
  for (int j = 0; j < 8; ++j) {
    const int k = hi * 8 + j;
    if (k < 18) {
      const int ci = k / 9, r9 = k - ci * 9;
      const int dy = r9 / 3, dx = r9 - dy * 3;
      off[j] = ci * IMG_CI + dy * IMG_STRIDE + dx;
      val[j] = 1;
    } else {
      off[j] = 0;
      val[j] = 0;
    }
  }
}

// B-frag: weights[K=32(18)][ch=16]; lane l15 = ch, elems k = hi*8+j.
__device__ __forceinline__ bf16x8 make_conv_bfrag(const float* __restrict__ cw,
                                                  int l15, int hi) {
  __hip_bfloat16 btmp[8];
#pragma unroll
  for (int j = 0; j < 8; ++j) {
    const int k = hi * 8 + j;
    btmp[j] = __float2bfloat16((k < 18) ? cw[l15 * 18 + k] : 0.0f);
  }
  return *(bf16x8*)btmp;
}

// A-frag for conv-row tile (local row yloc, x0..x0+15): lane l15 = px.
__device__ __forceinline__ bf16x8 make_conv_afrag(const __hip_bfloat16* __restrict__ imgp,
                                                  int yloc, int x0, int l15,
                                                  const int* off, const int* val) {
  const int base = yloc * IMG_STRIDE + x0 + l15;
  const __hip_bfloat16 z = __float2bfloat16(0.0f);
  __hip_bfloat16 atmp[8];
#pragma unroll
  for (int j = 0; j < 8; ++j) atmp[j] = val[j] ? imgp[base + off[j]] : z;
  return *(bf16x8*)atmp;
}

// ---------------- Encoder pass A: MFMA conv + sum/sumsq partials; + weight/bcol prep ----------------
// grid 2048 (512 img x 4 slabs), 256 thr (4 waves). Wave: 8 tile-pairs (2 MFMAs each).
__global__ __launch_bounds__(256) void enc_stats_prep(
    const float* __restrict__ x, const float* __restrict__ cw,
    float* __restrict__ bstats,
    const float* __restrict__ wih, const float* __restrict__ whh,
    const float* __restrict__ pw,
    const float* __restrict__ bih, const float* __restrict__ bhh,
    __hip_bfloat16* __restrict__ wihb, __hip_bfloat16* __restrict__ whhb,
    __hip_bfloat16* __restrict__ pwb, float* __restrict__ bcol) {
  {
    const int n1 = 1536 * 256, n2 = 1536 * 512, n3 = 256 * 512, n4 = 512 * 12;
    int i = blockIdx.x * 256 + threadIdx.x;
    int st = gridDim.x * 256;
    for (int j = i; j < n1 + n2 + n3 + n4; j += st) {
      if (j < n1) {
        int r = j >> 8, c = j & 255;
        wihb[j] = __float2bfloat16(wih[r * 258 + c]);
      } else if (j < n1 + n2) {
        int k = j - n1;
        whhb[k] = __float2bfloat16(whh[k]);
      } else if (j < n1 + n2 + n3) {
        int k = j - n1 - n2;
        pwb[k] = __float2bfloat16(pw[k]);
      } else {
        int k = j - n1 - n2 - n3;
        int col = k / 12, e = k - col * 12;
        float v = 0.0f;
        switch (e) {
          case 0: v = bih[col] + bhh[col]; break;
          case 1: v = bih[512 + col] + bhh[512 + col]; break;
          case 2: v = bih[1024 + col]; break;
          case 3: v = bhh[1024 + col]; break;
          case 4: v = wih[col * 258 + 256]; break;
          case 5: v = wih[col * 258 + 257]; break;
          case 6: v = wih[(512 + col) * 258 + 256]; break;
          case 7: v = wih[(512 + col) * 258 + 257]; break;
          case 8: v = wih[(1024 + col) * 258 + 256]; break;
          case 9: v = wih[(1024 + col) * 258 + 257]; break;
          default: v = 0.0f; break;
        }
        bcol[k] = v;
      }
    }
  }

  __shared__ __hip_bfloat16 imgp[2 * IMG_CI];
  __shared__ float redS[4][16], redQ[4][16];
  const int tid = threadIdx.x;
  const int b = blockIdx.x >> 2, slab = blockIdx.x & 3;
  const int wv = tid >> 6, lane = tid & 63;
  const int l15 = lane & 15, hi = lane >> 4;
  stage_slab_bf16(imgp, x + b * 8192, slab, tid);

  int off[8], val[8];
  make_k_offsets(hi, off, val);
  const bf16x8 bfrag = make_conv_bfrag(cw, l15, hi);
  __syncthreads();

  float sacc = 0.0f, qacc = 0.0f;
  const f32x4 zero4 = {0.f, 0.f, 0.f, 0.f};
#pragma unroll
  for (int tp = 0; tp < 8; ++tp) {
    const int tpi = wv * 8 + tp;
    const int y0 = (tpi >> 2) * 2, x0 = (tpi & 3) * 16;
    bf16x8 a0 = make_conv_afrag(imgp, y0, x0, l15, off, val);
    bf16x8 a1 = make_conv_afrag(imgp, y0 + 1, x0, l15, off, val);
    f32x4 c0 = __builtin_amdgcn_mfma_f32_16x16x32_bf16(a0, bfrag, zero4, 0, 0, 0);
    f32x4 c1 = __builtin_amdgcn_mfma_f32_16x16x32_bf16(a1, bfrag, zero4, 0, 0, 0);
#pragma unroll
    for (int i = 0; i < 4; ++i) {
      sacc += c0[i] + c1[i];
      qacc = fmaf(c0[i], c0[i], qacc);
      qacc = fmaf(c1[i], c1[i], qacc);
    }
  }
  // reduce across hi groups (lanes l15, l15+16, l15+32, l15+48)
  sacc += __shfl_down(sacc, 16); sacc += __shfl_down(sacc, 32);
  qacc += __shfl_down(qacc, 16); qacc += __shfl_down(qacc, 32);
  if (lane < 16) { redS[wv][l15] = sacc; redQ[wv][l15] = qacc; }
  __syncthreads();
  if (tid < 16)
    bstats[tid * 2048 + blockIdx.x] =
        redS[0][tid] + redS[1][tid] + redS[2][tid] + redS[3][tid];
  else if (tid < 32) {
    int c = tid - 16;
    bstats[tid * 2048 + blockIdx.x] =
        redQ[0][c] + redQ[1][c] + redQ[2][c] + redQ[3][c];
  }
}

// reduce: 32 blocks; block c sums contiguous bstats[c][0..2048) -> stats[c]
__global__ __launch_bounds__(256) void reduce_stats_k(const float* __restrict__ bstats,
                                                      float* __restrict__ stats) {
  __shared__ float acc[4];
  const int c = blockIdx.x, tid = threadIdx.x;
  const float4 v4 = *(const float4*)(bstats + c * 2048 + tid * 8);
  const float4 w4 = *(const float4*)(bstats + c * 2048 + tid * 8 + 4);
  float v = v4.x + v4.y + v4.z + v4.w + w4.x + w4.y + w4.z + w4.w;
#pragma unroll
  for (int off = 32; off >= 1; off >>= 1) v += __shfl_down(v, off);
  if ((tid & 63) == 0) acc[tid >> 6] = v;
  __syncthreads();
  if (tid == 0) stats[c] = acc[0] + acc[1] + acc[2] + acc[3];
}

// ---------------- Encoder pass B: MFMA conv + BN + relu + 2x2 maxpool -> pooled partials ----------------
__global__ __launch_bounds__(256) void enc_pool(const float* __restrict__ x,
                                                const float* __restrict__ cw,
                                                const float* __restrict__ stats,
                                                const float* __restrict__ gamma,
                                                const float* __restrict__ beta,
                                                float* __restrict__ pooledG) {
  __shared__ __hip_bfloat16 imgp[2 * IMG_CI];
  __shared__ float red[4][16];
  __shared__ float statsL[32];
  const int tid = threadIdx.x;
  const int b = blockIdx.x >> 2, slab = blockIdx.x & 3;
  const int wv = tid >> 6, lane = tid & 63;
  const int l15 = lane & 15, hi = lane >> 4;
  stage_slab_bf16(imgp, x + b * 8192, slab, tid);
  if (tid < 32) statsL[tid] = stats[tid];

  int off[8], val[8];
  make_k_offsets(hi, off, val);
  const bf16x8 bfrag = make_conv_bfrag(cw, l15, hi);
  __syncthreads();

  // BN scale/shift for this lane's channel (l15)
  const float invN = 1.0f / (512.0f * 4096.0f);
  const float m = statsL[l15] * invN;
  const float var = statsL[16 + l15] * invN - m * m;
  const float isd = rsqrtf(var + 1e-5f);
  const float scv = gamma[l15] * isd;
  const float shv = beta[l15] - m * scv;

  float psum = 0.0f;
  const f32x4 zero4 = {0.f, 0.f, 0.f, 0.f};
#pragma unroll
  for (int tp = 0; tp < 8; ++tp) {
    const int tpi = wv * 8 + tp;
    const int y0 = (tpi >> 2) * 2, x0 = (tpi & 3) * 16;
    bf16x8 a0 = make_conv_afrag(imgp, y0, x0, l15, off, val);
    bf16x8 a1 = make_conv_afrag(imgp, y0 + 1, x0, l15, off, val);
    f32x4 c0 = __builtin_amdgcn_mfma_f32_16x16x32_bf16(a0, bfrag, zero4, 0, 0, 0);
    f32x4 c1 = __builtin_amdgcn_mfma_f32_16x16x32_bf16(a1, bfrag, zero4, 0, 0, 0);
#pragma unroll
    for (int p = 0; p < 2; ++p) {
      const float v00 = fmaxf(fmaf(c0[2 * p + 0], scv, shv), 0.0f);
      const float v01 = fmaxf(fmaf(c0[2 * p + 1], scv, shv), 0.0f);
      const float v10 = fmaxf(fmaf(c1[2 * p + 0], scv, shv), 0.0f);
      const float v11 = fmaxf(fmaf(c1[2 * p + 1], scv, shv), 0.0f);
      psum += fmaxf(fmaxf(v00, v01), fmaxf(v10, v11));
    }
  }
  psum += __shfl_down(psum, 16);
  psum += __shfl_down(psum, 32);
  if (lane < 16) red[wv][l15] = psum;
  __syncthreads();
  if (tid < 16)
    pooledG[blockIdx.x * 16 + tid] = red[0][tid] + red[1][tid] + red[2][tid] + red[3][tid];
}

// ---------------- GRU gates, gate-per-wave: 512 blocks x 384 thr (6 waves) ----------------
__global__ __launch_bounds__(384) void gru_v2(
    const __hip_bfloat16* __restrict__ spb,
    const __hip_bfloat16* __restrict__ hb_in,
    __hip_bfloat16* __restrict__ hb_out,
    const __hip_bfloat16* __restrict__ wihb,   // [1536][256]
    const __hip_bfloat16* __restrict__ whhb,   // [1536][512]
    const float* __restrict__ bcol,            // [512][12] packed epilogue constants
    const float* __restrict__ actions,         // [512][16][2]
    const float* __restrict__ pooledG,         // [2048][16]
    const float* __restrict__ fcw,             // [256][16]
    const float* __restrict__ fcb,             // [256]
    float* __restrict__ out,
    int t) {
  __shared__ __hip_bfloat16 sF[8 * 64 * 8];    // 8KB:  s A-frags, frag-order
  __shared__ __hip_bfloat16 hF[16 * 64 * 8];   // 16KB: h A-frags, frag-order
  __shared__ float accL[4][2][256];            // 8KB (t=0: first 256 f reused as avg)
  const int tid = threadIdx.x;
  const int w = tid / 64, lane = tid & 63;
  const int l15 = lane & 15, hi = lane >> 4;
  const int cg = blockIdx.x, band = blockIdx.y;
  const int row0 = band * 16;
  const int ct = w & 1, g = w >> 1;

  if (t == 0) {
    float* avgF = &accL[0][0][0];
    if (tid < 256) {
      const int r = tid >> 4, k = tid & 15;
      const int img = row0 + r;
      const float v = pooledG[(img * 4 + 0) * 16 + k] + pooledG[(img * 4 + 1) * 16 + k] +
                      pooledG[(img * 4 + 2) * 16 + k] + pooledG[(img * 4 + 3) * 16 + k];
      avgF[r * 16 + k] = v * (1.0f / 1024.0f);
    }
    __syncthreads();
    for (int i = tid; i < 4096; i += 384) {
      const int kk = i >> 9, rem = i & 511, ln = rem >> 3, e = rem & 7;
      const int r = ln & 15;
      const int col = kk * 32 + (ln >> 4) * 8 + e;
      float v = fcb[col];
#pragma unroll
      for (int k = 0; k < 16; ++k) v = fmaf(avgF[r * 16 + k], fcw[col * 16 + k], v);
      sF[i] = __float2bfloat16(v);
      if (cg == 0) out[((size_t)(row0 + r) * TT + 0) * 256 + col] = v;
    }
  } else {
    for (int i = tid; i < 512; i += 384) {
      int kk = i >> 6, ln = i & 63;
      *(bf16x8*)(sF + i * 8) =
          *(const bf16x8*)(spb + (row0 + (ln & 15)) * 256 + kk * 32 + (ln >> 4) * 8);
    }
    for (int i = tid; i < 1024; i += 384) {
      int kk = i >> 6, ln = i & 63;
      *(bf16x8*)(hF + i * 8) =
          *(const bf16x8*)(hb_in + (row0 + (ln & 15)) * 512 + kk * 32 + (ln >> 4) * 8);
    }
  }
  __syncthreads();

  const int cj = cg * 32 + ct * 16;
  f32x4 accS = {0.f, 0.f, 0.f, 0.f}, accH = accS;
  {
    const __hip_bfloat16* B = wihb + (g * 512 + cj + l15) * 256 + hi * 8;
#pragma unroll
    for (int kk = 0; kk < 8; ++kk) {
      bf16x8 a = *(const bf16x8*)(sF + (kk * 64 + lane) * 8);
      accS = __builtin_amdgcn_mfma_f32_16x16x32_bf16(a, *(const bf16x8*)(B + kk * 32),
                                                     accS, 0, 0, 0);
    }
  }
  if (t > 0) {
    const __hip_bfloat16* B = whhb + (g * 512 + cj + l15) * 512 + hi * 8;
#pragma unroll
    for (int kk = 0; kk < 16; ++kk) {
      bf16x8 a = *(const bf16x8*)(hF + (kk * 64 + lane) * 8);
      accH = __builtin_amdgcn_mfma_f32_16x16x32_bf16(a, *(const bf16x8*)(B + kk * 32),
                                                     accH, 0, 0, 0);
    }
  }
  __syncthreads();
  if (g < 2) {
#pragma unroll
    for (int i = 0; i < 4; ++i)
      accL[g][ct][(hi * 4 + i) * 16 + l15] = accS[i] + accH[i];
  } else {
#pragma unroll
    for (int i = 0; i < 4; ++i) {
      accL[2][ct][(hi * 4 + i) * 16 + l15] = accS[i];
      accL[3][ct][(hi * 4 + i) * 16 + l15] = accH[i];
    }
  }
  __syncthreads();

  if (w < 2) {
    f32x4 vR = *(const f32x4*)&accL[0][w][lane * 4];
    f32x4 vZ = *(const f32x4*)&accL[1][w][lane * 4];
    f32x4 vXN = *(const f32x4*)&accL[2][w][lane * 4];
    f32x4 vHN = *(const f32x4*)&accL[3][w][lane * 4];
    const int r = lane >> 2;
    const int row = row0 + r;
    const float u0 = actions[row * 32 + t * 2 + 0];
    const float u1 = actions[row * 32 + t * 2 + 1];
#pragma unroll
    for (int j = 0; j < 4; ++j) {
      const int c = (lane & 3) * 4 + j;
      const int col = cg * 32 + w * 16 + c;
      const float4 b0 = *(const float4*)(bcol + col * 12);      // br,bz,bxn,bhn
      const float4 b1 = *(const float4*)(bcol + col * 12 + 4);  // wur,wvr,wuz,wvz
      const float4 b2 = *(const float4*)(bcol + col * 12 + 8);  // wun,wvn,-,-
      const float gr = vR[j] + b0.x + u0 * b1.x + u1 * b1.y;
      const float gz = vZ[j] + b0.y + u0 * b1.z + u1 * b1.w;
      const float gxn = vXN[j] + b0.z + u0 * b2.x + u1 * b2.y;
      const float ghn = vHN[j] + b0.w;
      const float rg = 1.0f / (1.0f + __expf(-gr));
      const float zg = 1.0f / (1.0f + __expf(-gz));
      float xn = gxn + rg * ghn;
      xn = fminf(fmaxf(xn, -15.0f), 15.0f);
      const float e = __expf(2.0f * xn);
      const float ng = (e - 1.0f) / (e + 1.0f);
      const float hp = (t > 0) ? (float)hb_in[row * 512 + col] : 0.0f;
      const float hnv = (1.0f - zg) * ng + zg * hp;
      hb_out[row * 512 + col] = __float2bfloat16(hnv);
    }
  }
}

// ---------------- pred, split-K-4: 512 blocks x 256 thr (4 waves) ----------------
__global__ __launch_bounds__(256) void pred_v2(
    const __hip_bfloat16* __restrict__ hb,
    const __hip_bfloat16* __restrict__ pwb,    // [256][512]
    const float* __restrict__ pb,
    float* __restrict__ out,
    __hip_bfloat16* __restrict__ spb,
    int slot) {
  __shared__ float accL[4][256];
  const int tid = threadIdx.x;
  const int w = tid >> 6, lane = tid & 63;
  const int l15 = lane & 15, hi = lane >> 4;
  const int pcg = blockIdx.x, band = blockIdx.y;
  const int row0 = band * 16, pc0 = pcg * 16;
  f32x4 acc = {0.f, 0.f, 0.f, 0.f};
  const __hip_bfloat16* A = hb + (row0 + l15) * 512 + w * 128 + hi * 8;
  const __hip_bfloat16* B = pwb + (pc0 + l15) * 512 + w * 128 + hi * 8;
#pragma unroll
  for (int kk = 0; kk < 4; ++kk)
    acc = __builtin_amdgcn_mfma_f32_16x16x32_bf16(*(const bf16x8*)(A + kk * 32),
                                                  *(const bf16x8*)(B + kk * 32),
                                                  acc, 0, 0, 0);
#pragma unroll
  for (int i = 0; i < 4; ++i) accL[w][(hi * 4 + i) * 16 + l15] = acc[i];
  __syncthreads();
  if (w == 0) {
    f32x4 p0 = *(const f32x4*)&accL[0][lane * 4];
    f32x4 p1 = *(const f32x4*)&accL[1][lane * 4];
    f32x4 p2 = *(const f32x4*)&accL[2][lane * 4];
    f32x4 p3 = *(const f32x4*)&accL[3][lane * 4];
    const int r = lane >> 2;
    const int row = row0 + r;
    float4 ov;
    float* po = &ov.x;
#pragma unroll
    for (int j = 0; j < 4; ++j) {
      const int c = (lane & 3) * 4 + j;
      const int col = pc0 + c;
      float v = p0[j] + p1[j] + p2[j] + p3[j] + pb[col];
      v = fmaxf(v, 0.0f);
      po[j] = v;
      spb[row * 256 + col] = __float2bfloat16(v);
    }
    *(float4*)(out + ((size_t)row * TT + slot) * 256 + pc0 + (lane & 3) * 4) = ov;
  }
}

extern "C" void kernel_launch(void* const* d_in, const int* in_sizes, int n_in,
                              void* d_out, int out_size, void* d_ws, size_t ws_size,
                              hipStream_t stream) {
  const float* x       = (const float*)d_in[0];
  const float* actions = (const float*)d_in[1];
  const float* cw      = (const float*)d_in[2];
  const float* gamma   = (const float*)d_in[3];
  const float* beta    = (const float*)d_in[4];
  const float* fcw     = (const float*)d_in[5];
  const float* fcb     = (const float*)d_in[6];
  const float* wih     = (const float*)d_in[7];
  const float* whh     = (const float*)d_in[8];
  const float* bih     = (const float*)d_in[9];
  const float* bhh     = (const float*)d_in[10];
  const float* pw      = (const float*)d_in[11];
  const float* pb      = (const float*)d_in[12];
  float* out = (float*)d_out;
  float* ws  = (float*)d_ws;

  float* bstats  = ws + OFF_BSTATS;
  float* stats   = ws + OFF_STATS;
  float* pooledG = ws + OFF_POOLED;
  float* bcol    = ws + OFF_BCOL;
  __hip_bfloat16* spb  = (__hip_bfloat16*)(ws + OFF_SPB);
  __hip_bfloat16* pwb  = (__hip_bfloat16*)(ws + OFF_PWB);
  __hip_bfloat16* wihb = (__hip_bfloat16*)(ws + OFF_WIHB);
  __hip_bfloat16* whhb = (__hip_bfloat16*)(ws + OFF_WHHB);
  __hip_bfloat16* hb0  = (__hip_bfloat16*)(ws + OFF_HB);
  __hip_bfloat16* hb1  = hb0 + 512 * 512;

  enc_stats_prep<<<dim3(2048), dim3(256), 0, stream>>>(x, cw, bstats, wih, whh, pw,
                                                       bih, bhh, wihb, whhb, pwb, bcol);
  reduce_stats_k<<<dim3(32), dim3(256), 0, stream>>>(bstats, stats);
  enc_pool<<<dim3(2048), dim3(256), 0, stream>>>(x, cw, stats, gamma, beta, pooledG);
  for (int t = 0; t < TM1; ++t) {
    __hip_bfloat16* hbi = (t & 1) ? hb1 : hb0;
    __hip_bfloat16* hbo = (t & 1) ? hb0 : hb1;
    gru_v2<<<dim3(16, 32), dim3(384), 0, stream>>>(spb, hbi, hbo, wihb, whhb,
                                                   bcol, actions, pooledG, fcw, fcb,
                                                   out, t);
    pred_v2<<<dim3(16, 32), dim3(256), 0, stream>>>(hbo, pwb, pb, out, spb, t + 1);
  }
}